// Round 13
// baseline (178.656 us; speedup 1.0000x reference)
//
#include <hip/hip_runtime.h>
#include <math.h>

#define CK __restrict__

constexpr int CH = 256;
constexpr int HW = 1024;   // 32*32

typedef __attribute__((ext_vector_type(8))) short short8;
typedef __attribute__((ext_vector_type(4))) float f32x4;
typedef __attribute__((ext_vector_type(2))) float v2f;

__device__ __forceinline__ ushort f2b(float x) {   // fp32 -> bf16 RNE
    union { float f; unsigned int u; } a; a.f = x;
    unsigned int r = (a.u + 0x7FFFu + ((a.u >> 16) & 1u)) >> 16;
    return (ushort)r;
}
__device__ __forceinline__ short8 ld8(const ushort* p) { return *(const short8*)p; }
__device__ __forceinline__ float u2f(unsigned int u) {
    union { unsigned int u; float f; } a; a.u = u; return a.f;
}
__device__ __forceinline__ float b2f(ushort us) { return u2f((unsigned int)us << 16); }

// ---------------------------------------------------------------------------
// prep: blocks 0..255  : four 256x256 weights -> bf16
//       blocks 256..383: x fp32 [b][c][n] -> xT bf16 [b][n][c]
//       blocks 384..391: rpe head -> padded bf16 x-pair table, pitch 67
// ---------------------------------------------------------------------------
__global__ __launch_bounds__(256) void prep(const float* CK w0, const float* CK w1,
                                            const float* CK w2, const float* CK w3,
                                            ushort* CK o0, ushort* CK o1,
                                            ushort* CK o2, ushort* CK o3,
                                            const float* CK x, ushort* CK xT,
                                            const float* CK rpe, unsigned int* CK rpetab) {
    const int bid = blockIdx.x, t = threadIdx.x;
    if (bid < 256) {
        const float* src; ushort* dst;
        switch (bid >> 6) {
            case 0: src = w0; dst = o0; break;
            case 1: src = w1; dst = o1; break;
            case 2: src = w2; dst = o2; break;
            default: src = w3; dst = o3; break;
        }
        const int i = (bid & 63) * 256 + t;
        float4 v = ((const float4*)src)[i];
        ushort4 r; r.x = f2b(v.x); r.y = f2b(v.y); r.z = f2b(v.z); r.w = f2b(v.w);
        ((ushort4*)dst)[i] = r;
    } else if (bid < 384) {
        const int b2 = bid - 256;          // 0..127
        const int c8 = b2 & 31, b = b2 >> 5;
        for (int nn = 0; nn < 4; nn++) {
            const int n = nn * 256 + t;
            union { ushort u[8]; short8 s; } pk;
#pragma unroll
            for (int j = 0; j < 8; j++) pk.u[j] = f2b(x[(b * 256 + c8 * 8 + j) * HW + n]);
            *(short8*)(xT + b * 262144 + n * 256 + c8 * 8) = pk.s;
        }
    } else {
        const int h = bid - 384;           // head 0..7
        const float* rp = rpe + h * 3969;
        unsigned int* dst = rpetab + h * 4356;
        for (int i = t; i < 4356; i += 256) {
            int y = i / 67, x2 = i - y * 67;
            int yy = y - 1, xx = x2 - 1;
            bool vy = (yy >= 0) && (yy < 63) && (y < 65);
            float a  = (vy && xx >= 0 && xx < 63) ? rp[yy * 63 + xx] : 0.f;
            float bb = (vy && xx >= -1 && xx < 62) ? rp[yy * 63 + xx + 1] : 0.f;
            dst[i] = (unsigned int)f2b(a) | ((unsigned int)f2b(bb) << 16);
        }
    }
}

// ---------------------------------------------------------------------------
// MFMA GEMM, n-split: 64m x 32n block, grid (32 nt, 4 mt, 4 b) = 512 blocks
// (2 blocks/CU).  Wave = 32m x 16n, 2 independent acc chains.
// bf16 out: Q = W*xT + bias.
// ---------------------------------------------------------------------------
__global__ __launch_bounds__(256) void gemm_q(const ushort* CK AT, const ushort* CK W,
                                              const float* CK bias, ushort* CK Y) {
    const int b = blockIdx.z;
    const int t = threadIdx.x, w = t >> 6, l = t & 63;
    const int lm = l & 15, qd = l >> 4;
    const int m0 = blockIdx.y * 64 + (w & 1) * 32;
    const int nb_ = blockIdx.x * 32 + (w >> 1) * 16;
    const ushort* A = AT + b * 262144 + nb_ * 256;
    const ushort* Bm = W + m0 * 256;
    f32x4 acc[2] = {};
#pragma unroll
    for (int k0 = 0; k0 < 8; k0++) {
        const int ko = k0 * 32 + qd * 8;
        short8 a0 = ld8(A + lm * 256 + ko);
        short8 b0 = ld8(Bm + lm * 256 + ko);
        short8 b1 = ld8(Bm + (16 + lm) * 256 + ko);
        acc[0] = __builtin_amdgcn_mfma_f32_16x16x32_bf16(a0, b0, acc[0], 0, 0, 0);
        acc[1] = __builtin_amdgcn_mfma_f32_16x16x32_bf16(a0, b1, acc[1], 0, 0, 0);
    }
#pragma unroll
    for (int im = 0; im < 2; im++) {
        const int m = m0 + im * 16 + lm;
        const float bs = bias[m];
        ushort4 r;
        r.x = f2b(acc[im][0] + bs); r.y = f2b(acc[im][1] + bs);
        r.z = f2b(acc[im][2] + bs); r.w = f2b(acc[im][3] + bs);
        *(ushort4*)(Y + b * 262144 + m * HW + nb_ + qd * 4) = r;
    }
}

// ---------------------------------------------------------------------------
// Fused K+V MFMA GEMM, n-split (64m x 32n, grid (32,4,4)); bf16
// fragment-linear outputs (formats unchanged).
// ---------------------------------------------------------------------------
__global__ __launch_bounds__(256) void gemm_kv(const ushort* CK AT,
                                               const ushort* CK Wk, const float* CK bk, ushort* CK kbt,
                                               const ushort* CK Wv, const float* CK bv, ushort* CK vbs) {
    const int b = blockIdx.z;
    const int t = threadIdx.x, w = t >> 6, l = t & 63;
    const int lm = l & 15, qd = l >> 4;
    const int m0 = blockIdx.y * 64 + (w & 1) * 32;
    const int nb_ = blockIdx.x * 32 + (w >> 1) * 16;
    const ushort* A = AT + b * 262144 + nb_ * 256;
    const ushort* Bk = Wk + m0 * 256;
    const ushort* Bv = Wv + m0 * 256;
    f32x4 akT[2] = {}, av[2] = {};
#pragma unroll
    for (int k0 = 0; k0 < 8; k0++) {
        const int ko = k0 * 32 + qd * 8;
        short8 a0 = ld8(A + lm * 256 + ko);
        short8 k0f = ld8(Bk + lm * 256 + ko);
        short8 k1f = ld8(Bk + (16 + lm) * 256 + ko);
        short8 v0f = ld8(Bv + lm * 256 + ko);
        short8 v1f = ld8(Bv + (16 + lm) * 256 + ko);
        akT[0] = __builtin_amdgcn_mfma_f32_16x16x32_bf16(k0f, a0, akT[0], 0, 0, 0);
        akT[1] = __builtin_amdgcn_mfma_f32_16x16x32_bf16(k1f, a0, akT[1], 0, 0, 0);
        av[0]  = __builtin_amdgcn_mfma_f32_16x16x32_bf16(a0, v0f, av[0], 0, 0, 0);
        av[1]  = __builtin_amdgcn_mfma_f32_16x16x32_bf16(a0, v1f, av[1], 0, 0, 0);
    }
#pragma unroll
    for (int im = 0; im < 2; im++) {
        {   // K: lane holds K[c0+r][n], c0 = m0+im*16+qd*4, n = nb_+lm
            const int c0 = m0 + im * 16 + qd * 4;
            const int n  = nb_ + lm;
            const int bh = b * 8 + (c0 >> 5);
            const int qdk = (c0 & 31) >> 3, co4 = c0 & 7;
            const int nc = n >> 7, nbk = (n >> 4) & 7, lmk = n & 15;
            const float4 bks = *(const float4*)(bk + c0);
            ushort4 r4;
            r4.x = f2b(akT[im][0] + bks.x);
            r4.y = f2b(akT[im][1] + bks.y);
            r4.z = f2b(akT[im][2] + bks.z);
            r4.w = f2b(akT[im][3] + bks.w);
            *(ushort4*)(kbt + ((bh * 8 + nc) * 512 + nbk * 64 + qdk * 16 + lmk) * 8 + co4) = r4;
        }
        {   // V: lane holds V[c][nbase+r], c = m0+im*16+lm, nbase = nb_+qd*4
            const int c = m0 + im * 16 + lm;
            const int bh = b * 8 + (c >> 5);
            const float bs = bv[c];
            const int cb = (c & 31) >> 4, lmv = c & 15;
            const int nbase = nb_ + qd * 4;
            const int nc = nbase >> 7, kc = (nbase >> 5) & 3;
            const int qdv = (nbase >> 3) & 3, co0 = nbase & 7;
            ushort4 r4;
            r4.x = f2b(av[im][0] + bs); r4.y = f2b(av[im][1] + bs);
            r4.z = f2b(av[im][2] + bs); r4.w = f2b(av[im][3] + bs);
            *(ushort4*)(vbs + ((bh * 8 + nc) * 512 + (cb * 4 + kc) * 64 + qdv * 16 + lmv) * 8 + co0) = r4;
        }
    }
}

// ---------------------------------------------------------------------------
// FUSED depthwise-5x5 + LayerNorm + GELU + proj + tanh -> pos + bilinear
// sample (r12, unchanged).
// ---------------------------------------------------------------------------
__global__ __launch_bounds__(256) void dwln(const ushort* CK q, const float* CK wdw,
                                            const float* CK bdw, const float* CK ln_g,
                                            const float* CK ln_b, const float* CK wpj,
                                            const float* CK x,
                                            float* CK out_pos, float* CK out_ref,
                                            float2* CK pos_sc, ushort* CK xsT) {
    __shared__ __align__(16) ushort qs[64 * 218];   // [ch][6 rows x 36 cols], pitch 218
    __shared__ __align__(16) float offs[64][68];    // [pix][ch], pitch 68
    const int bid = blockIdx.x, t = threadIdx.x;
    const int bg = bid >> 4, rp = bid & 15;         // rp = 2-row strip

    {
        const int ch = t & 63;
        const int r6a = t >> 6;                     // 0..3
#pragma unroll
        for (int pass = 0; pass < 2; pass++) {
            const int r6 = (pass == 0) ? r6a : (4 + r6a);
            if (pass == 1 && r6a >= 2) break;
            const int grow = rp * 2 - 2 + r6;
            unsigned int* dst = (unsigned int*)(qs + ch * 218 + r6 * 36);
            if (grow >= 0 && grow <= 31) {
                const unsigned int* src = (const unsigned int*)(q + (bg * 64 + ch) * 1024 + grow * 32);
                dst[0] = 0;
#pragma unroll
                for (int k2 = 0; k2 < 16; k2++) dst[1 + k2] = src[k2];   // cols 0..31
                dst[17] = 0;
            } else {
#pragma unroll
                for (int k2 = 0; k2 < 18; k2++) dst[k2] = 0;
            }
        }
    }
    __syncthreads();

    {
        const int ch = t >> 2, pg = t & 3;
        const int pr = pg >> 1, c0 = (pg & 1) * 16;
        float w[25];
#pragma unroll
        for (int i = 0; i < 25; i++) w[i] = wdw[ch * 25 + i];
        const float bb = bdw[ch];
        float nb[5][20];
#pragma unroll
        for (int r = 0; r < 5; r++) {
            const unsigned int* row = (const unsigned int*)(qs + ch * 218 + (pr + r) * 36 + c0);
#pragma unroll
            for (int u = 0; u < 10; u++) {
                const unsigned int v = row[u];
                nb[r][u * 2]     = u2f(v << 16);
                nb[r][u * 2 + 1] = u2f(v & 0xFFFF0000u);
            }
        }
#pragma unroll
        for (int j = 0; j < 16; j++) {
            float s = bb;
#pragma unroll
            for (int ky = 0; ky < 5; ky++)
#pragma unroll
                for (int kx = 0; kx < 5; kx++) s += nb[ky][j + kx] * w[ky * 5 + kx];
            offs[pr * 32 + c0 + j][ch] = s;
        }
    }
    __syncthreads();

    const int pix_l = t >> 2, qtr = t & 3;
    const int n = rp * 64 + pix_l;
    const int gid = bg * 1024 + n;
    const int c0 = qtr * 16;
    float v[16];
    {
        const float4* ov = (const float4*)&offs[pix_l][c0];
        const float4 V0 = ov[0], V1 = ov[1], V2 = ov[2], V3 = ov[3];
        v[0] = V0.x;  v[1] = V0.y;  v[2] = V0.z;  v[3] = V0.w;
        v[4] = V1.x;  v[5] = V1.y;  v[6] = V1.z;  v[7] = V1.w;
        v[8] = V2.x;  v[9] = V2.y;  v[10] = V2.z; v[11] = V2.w;
        v[12] = V3.x; v[13] = V3.y; v[14] = V3.z; v[15] = V3.w;
    }
    float s1 = 0.f;
#pragma unroll
    for (int j = 0; j < 16; j++) s1 += v[j];
    s1 += __shfl_xor(s1, 1); s1 += __shfl_xor(s1, 2);
    const float mean = s1 * 0.015625f;
    float s2 = 0.f;
#pragma unroll
    for (int j = 0; j < 16; j++) { float d = v[j] - mean; s2 += d * d; }
    s2 += __shfl_xor(s2, 1); s2 += __shfl_xor(s2, 2);
    const float rs = rsqrtf(s2 * 0.015625f + 1e-5f);
    float p0 = 0.f, p1 = 0.f;
#pragma unroll
    for (int j = 0; j < 16; j++) {
        float vv = (v[j] - mean) * rs * ln_g[c0 + j] + ln_b[c0 + j];
        float gl = 0.5f * vv * (1.f + erff(vv * 0.70710678118654752f));
        p0 += gl * wpj[c0 + j];
        p1 += gl * wpj[64 + c0 + j];
    }
    p0 += __shfl_xor(p0, 1); p0 += __shfl_xor(p0, 2);
    p1 += __shfl_xor(p1, 1); p1 += __shfl_xor(p1, 2);
    const int ii = n >> 5, jj = n & 31;
    const float r0 = (jj + 0.5f) * 0.0625f - 1.f;   // ref ch0 <- column (meshgrid-xy)
    const float r1 = (ii + 0.5f) * 0.0625f - 1.f;   // ref ch1 <- row
    const float pos0 = tanhf(p0) * 0.0625f + r0;
    const float pos1 = tanhf(p1) * 0.0625f + r1;
    if (qtr == 0) {
        out_pos[gid * 2] = pos0; out_pos[gid * 2 + 1] = pos1;
        out_ref[gid * 2] = r0;   out_ref[gid * 2 + 1] = r1;
        pos_sc[gid].x = pos0 * 15.5f; pos_sc[gid].y = pos1 * 15.5f;
    }
    const float gx = (pos1 + 1.f) * 15.5f, gy = (pos0 + 1.f) * 15.5f;
    const float x0f = floorf(gx), y0f = floorf(gy);
    const float wx1 = gx - x0f, wx0 = 1.f - wx1, wy1 = gy - y0f, wy0 = 1.f - wy1;
    const bool vx0 = (x0f >= 0.f) && (x0f <= 31.f);
    const bool vx1 = (x0f >= -1.f) && (x0f <= 30.f);
    const bool vy0 = (y0f >= 0.f) && (y0f <= 31.f);
    const bool vy1 = (y0f >= -1.f) && (y0f <= 30.f);
    const int xi0 = (int)fminf(fmaxf(x0f, 0.f), 31.f);
    const int xi1 = (int)fminf(fmaxf(x0f + 1.f, 0.f), 31.f);
    const int yi0 = (int)fminf(fmaxf(y0f, 0.f), 31.f);
    const int yi1 = (int)fminf(fmaxf(y0f + 1.f, 0.f), 31.f);
    const float w00 = (vy0 && vx0) ? wy0 * wx0 : 0.f;
    const float w01 = (vy0 && vx1) ? wy0 * wx1 : 0.f;
    const float w10 = (vy1 && vx0) ? wy1 * wx0 : 0.f;
    const float w11 = (vy1 && vx1) ? wy1 * wx1 : 0.f;
    const int o00 = yi0 * 32 + xi0, o01 = yi0 * 32 + xi1;
    const int o10 = yi1 * 32 + xi0, o11 = yi1 * 32 + xi1;
    const int b = bg >> 2, g = bg & 3;
    const float* xb = x + bg * 64 * HW;
    ushort* xo = xsT + b * 262144 + n * 256 + g * 64 + c0;
#pragma unroll
    for (int j4 = 0; j4 < 4; j4++) {
        ushort4 r4;
        float vals[4];
#pragma unroll
        for (int j = 0; j < 4; j++) {
            const float* p = xb + (c0 + j4 * 4 + j) * HW;
            vals[j] = w00 * p[o00] + w01 * p[o01] + w10 * p[o10] + w11 * p[o11];
        }
        r4.x = f2b(vals[0]); r4.y = f2b(vals[1]); r4.z = f2b(vals[2]); r4.w = f2b(vals[3]);
        *(ushort4*)(xo + j4 * 4) = r4;
    }
}

// ---------------------------------------------------------------------------
// MFMA flash attention, n-split x4, fixed-reference softmax.
// launch_bounds (256, 6): LDS 26.6K x 6 = 159.7K fits -> 6 blocks/CU cap.
// ---------------------------------------------------------------------------
__global__ __launch_bounds__(256, 6) void attn_part(const ushort* CK q, const ushort* CK kbt,
                                                    const ushort* CK vbs, const float2* CK pos_sc,
                                                    const unsigned int* CK rpetab,
                                                    ushort* CK partO, float* CK lbuf) {
    __shared__ __align__(16) unsigned int rpe_pr[4356];      // 65 x pitch-67 bf16-pairs
    __shared__ __align__(16) ushort Pl[4][1088];             // per-wave 4 blk x 272
    const int bh = blockIdx.y, quarter = blockIdx.z;
    const int b = bh >> 3, nh = bh & 7, bg = bh >> 1;
    const int t = threadIdx.x;
    const int w = t >> 6, l = t & 63;
    const int lm = l & 15, qd = l >> 4;

    {
        const uint4* src4 = (const uint4*)(rpetab + nh * 4356);
        uint4* dst4 = (uint4*)rpe_pr;
        for (int i = t; i < 1089; i += 256) dst4[i] = src4[i];
    }
    __syncthreads();

    const int m = blockIdx.x * 64 + w * 16 + lm;
    short8 qf;
    {
        union { ushort u[8]; short8 s; } pk;
        const ushort* qb = q + (b * 256 + nh * 32) * HW + m;
#pragma unroll
        for (int j = 0; j < 8; j++) pk.u[j] = qb[(qd * 8 + j) * HW];
        qf = pk.s;
    }
    const float qg0 = ((m & 31) + 0.5f) * 0.0625f - 1.f;
    const float qg1 = ((m >> 5) + 0.5f) * 0.0625f - 1.f;
    const float ax = 31.f + 15.5f * qg1;   // gx = ax - sc_pos1  (>= 0 always)
    const float ay = 31.f + 15.5f * qg0;   // gy = ay - sc_pos0  (>= 0 always)

    f32x4 oacc0 = {0.f, 0.f, 0.f, 0.f}, oacc1 = {0.f, 0.f, 0.f, 0.f};
    float rsum = 0.f;
    ushort* PlW = Pl[w];
    const float2* pbase = pos_sc + bg * 1024;

    for (int nc = quarter * 2; nc < quarter * 2 + 2; nc++) {
        const ushort* kg = kbt + (bh * 8 + nc) * 4096;
        const ushort* vg = vbs + (bh * 8 + nc) * 4096;

#pragma unroll
        for (int g = 0; g < 2; g++) {                 // 64-n groups
            f32x4 sT[4];
#pragma unroll
            for (int s = 0; s < 4; s++) {
                const int nb = g * 4 + s;
                sT[s] = __builtin_amdgcn_mfma_f32_16x16x32_bf16(
                            ld8(kg + (nb * 64 + l) * 8), qf,
                            (f32x4){0.f, 0.f, 0.f, 0.f}, 0, 0, 0);
            }
#pragma unroll
            for (int s = 0; s < 4; s++) {
                const float4* pp = (const float4*)(pbase + nc * 128 + (g * 4 + s) * 16 + qd * 4);
                const float4 pa = pp[0], pb_ = pp[1];
                const float psx[4] = {pa.x, pa.z, pb_.x, pb_.z};
                const float psy[4] = {pa.y, pa.w, pb_.y, pb_.w};
#pragma unroll
                for (int rp = 0; rp < 2; rp++) {
                    v2f gx = {ax - psy[rp * 2], ax - psy[rp * 2 + 1]};
                    v2f gy = {ay - psx[rp * 2], ay - psx[rp * 2 + 1]};
                    const int xi0 = (int)gx.x, xi1 = (int)gx.y;   // trunc == floor (>=0)
                    const int yi0 = (int)gy.x, yi1 = (int)gy.y;
                    v2f wx = gx - (v2f){(float)xi0, (float)xi1};
                    v2f wy = gy - (v2f){(float)yi0, (float)yi1};
                    const int idxA = yi0 * 67 + xi0 + 68;
                    const int idxB = yi1 * 67 + xi1 + 68;
                    const unsigned int a0 = rpe_pr[idxA], a1 = rpe_pr[idxA + 67];
                    const unsigned int b0 = rpe_pr[idxB], b1 = rpe_pr[idxB + 67];
                    v2f tA = {u2f(a0 << 16), u2f(a0 & 0xFFFF0000u)};
                    v2f bA = {u2f(a1 << 16), u2f(a1 & 0xFFFF0000u)};
                    v2f tB = {u2f(b0 << 16), u2f(b0 & 0xFFFF0000u)};
                    v2f bB = {u2f(b1 << 16), u2f(b1 & 0xFFFF0000u)};
                    v2f vA = tA + wy.x * (bA - tA);
                    v2f vB = tB + wy.y * (bB - tB);
                    const float biasA = vA.x + wx.x * (vA.y - vA.x);
                    const float biasB = vB.x + wx.y * (vB.y - vB.x);
                    sT[s][rp * 2]     = sT[s][rp * 2]     * 0.17677669529663687f + biasA;
                    sT[s][rp * 2 + 1] = sT[s][rp * 2 + 1] * 0.17677669529663687f + biasB;
                }
            }
            // P = exp(s) -> wave-private LDS; per-lane denominator accumulate
#pragma unroll
            for (int s = 0; s < 4; s++) {
                float e0 = __expf(sT[s][0]);
                float e1 = __expf(sT[s][1]);
                float e2 = __expf(sT[s][2]);
                float e3 = __expf(sT[s][3]);
                rsum += (e0 + e1) + (e2 + e3);
                uint2 pk;
                pk.x = (unsigned int)f2b(e0) | ((unsigned int)f2b(e1) << 16);
                pk.y = (unsigned int)f2b(e2) | ((unsigned int)f2b(e3) << 16);
                *(uint2*)(PlW + s * 272 + l * 4) = pk;
            }
#pragma unroll
            for (int kc = 0; kc < 2; kc++) {
                const ushort* pb2 = PlW + (kc * 2 + (qd >> 1)) * 272 + (qd & 1) * 128 + lm * 4;
                union { uint2 u[2]; short8 s; } pfu;
                pfu.u[0] = *(const uint2*)pb2;
                pfu.u[1] = *(const uint2*)(pb2 + 64);
                const int kv = g * 2 + kc;
                oacc0 = __builtin_amdgcn_mfma_f32_16x16x32_bf16(ld8(vg + (kv * 64 + l) * 8), pfu.s, oacc0, 0, 0, 0);
                oacc1 = __builtin_amdgcn_mfma_f32_16x16x32_bf16(ld8(vg + ((4 + kv) * 64 + l) * 8), pfu.s, oacc1, 0, 0, 0);
            }
        }
    }

    // single cross-lane denominator reduction at the end
    rsum += __shfl_xor(rsum, 16);
    rsum += __shfl_xor(rsum, 32);

    ushort* po = partO + (((quarter * 32 + bh) * 1024 + m) * 32) + qd * 4;
    ushort4 r04, r14;
    r04.x = f2b(oacc0[0]); r04.y = f2b(oacc0[1]); r04.z = f2b(oacc0[2]); r04.w = f2b(oacc0[3]);
    r14.x = f2b(oacc1[0]); r14.y = f2b(oacc1[1]); r14.z = f2b(oacc1[2]); r14.w = f2b(oacc1[3]);
    *(ushort4*)po = r04;
    *(ushort4*)(po + 16) = r14;
    if (qd == 0) lbuf[(quarter * 32 + bh) * 1024 + m] = rsum;
}

// ---------------------------------------------------------------------------
// Output GEMM with fused 4-way combine, n-split (64m x 32n, grid (32,4,4)).
// ---------------------------------------------------------------------------
__global__ __launch_bounds__(256) void gemm_oc(const ushort* CK partO, const float* CK lbuf,
                                               const ushort* CK W, const float* CK bias,
                                               float* CK Y) {
    __shared__ __align__(16) float ew[32][8];      // 1 KB: 1/sum_l per (pix, head)
    const int b = blockIdx.z;
    const int t = threadIdx.x, w = t >> 6, l = t & 63;
    const int lm = l & 15, qd = l >> 4;
    const int m0 = blockIdx.y * 64 + (w & 1) * 32;
    const int nq16 = (w >> 1) * 16;
    const int nblk = blockIdx.x * 32;

    {   // 256 (pix, head) pairs, one per thread
        const int pix = t >> 3, head = t & 7;
        const int mg = nblk + pix;
        const int bh = b * 8 + head;
        float den = 0.f;
#pragma unroll
        for (int q2 = 0; q2 < 4; q2++) den += lbuf[(q2 * 32 + bh) * 1024 + mg];
        ew[pix][head] = 1.f / den;
    }
    __syncthreads();

    const ushort* Bm = W + m0 * 256;
    f32x4 acc[2] = {};
#pragma unroll
    for (int k0 = 0; k0 < 8; k0++) {
        const int ko = k0 * 32 + qd * 8;
        const int pix_l = nq16 + lm;
        const int mg = nblk + pix_l;
        const ushort* pbq = partO + ((b * 8 + k0) * 1024 + mg) * 32 + qd * 8;
        const float inv = ew[pix_l][k0];
        float a8[8] = {};
#pragma unroll
        for (int q2 = 0; q2 < 4; q2++) {
            union { ushort u[8]; short8 s; } pv;
            pv.s = ld8(pbq + q2 * 1048576);
#pragma unroll
            for (int j = 0; j < 8; j++) a8[j] += b2f(pv.u[j]);
        }
        union { ushort u[8]; short8 s; } af;
#pragma unroll
        for (int j = 0; j < 8; j++) af.u[j] = f2b(a8[j] * inv);
        short8 b0 = ld8(Bm + lm * 256 + ko);
        short8 b1 = ld8(Bm + (16 + lm) * 256 + ko);
        acc[0] = __builtin_amdgcn_mfma_f32_16x16x32_bf16(af.s, b0, acc[0], 0, 0, 0);
        acc[1] = __builtin_amdgcn_mfma_f32_16x16x32_bf16(af.s, b1, acc[1], 0, 0, 0);
    }
#pragma unroll
    for (int im = 0; im < 2; im++) {
        const int mo = m0 + im * 16 + lm;
        const float bs = bias[mo];
        float4 r;
        r.x = acc[im][0] + bs; r.y = acc[im][1] + bs;
        r.z = acc[im][2] + bs; r.w = acc[im][3] + bs;
        *(float4*)(Y + b * 262144 + mo * HW + nblk + nq16 + qd * 4) = r;
    }
}

// ---------------------------------------------------------------------------
extern "C" void kernel_launch(void* const* d_in, const int* in_sizes, int n_in,
                              void* d_out, int out_size, void* d_ws, size_t ws_size,
                              hipStream_t stream) {
    (void)in_sizes; (void)n_in; (void)out_size; (void)ws_size;
    const float* x   = (const float*)d_in[0];
    const float* wq  = (const float*)d_in[1];
    const float* bq  = (const float*)d_in[2];
    const float* wdw = (const float*)d_in[3];
    const float* bdw = (const float*)d_in[4];
    const float* lng = (const float*)d_in[5];
    const float* lnb = (const float*)d_in[6];
    const float* wpj = (const float*)d_in[7];
    const float* wk  = (const float*)d_in[8];
    const float* bk  = (const float*)d_in[9];
    const float* wv  = (const float*)d_in[10];
    const float* bv  = (const float*)d_in[11];
    const float* wo  = (const float*)d_in[12];
    const float* bo  = (const float*)d_in[13];
    const float* rpe = (const float*)d_in[14];
    float* outp = (float*)d_out;
    char* base = (char*)d_ws;
    const size_t MB = 1 << 20;

    ushort* q_b    = (ushort*)(base);                       // 2 MB  bf16 q
    ushort* kbt    = (ushort*)(base + 2 * MB);              // 2 MB
    ushort* vbs    = (ushort*)(base + 4 * MB);              // 2 MB
    // overlay @6MB..14MB: {xT 2MB @10, xsT 2MB @12} then partO 8MB @6
    ushort* xT     = (ushort*)(base + 10 * MB);
    ushort* xsT    = (ushort*)(base + 12 * MB);
    ushort* partO  = (ushort*)(base + 6 * MB);
    float*  lbuf   = (float*)(base + 14 * MB);              // 512 KB
    ushort* wqb    = (ushort*)(base + 15 * MB);
    ushort* wkb    = (ushort*)(base + 15 * MB + 131072);
    ushort* wvb    = (ushort*)(base + 15 * MB + 262144);
    ushort* wob    = (ushort*)(base + 15 * MB + 393216);
    float2* pos_sc = (float2*)(base + 15 * MB + 524288);    // 128 KB
    unsigned int* rpetab = (unsigned int*)(base + 15 * MB + 655360);  // 139 KB

    prep<<<392, 256, 0, stream>>>(wq, wk, wv, wo, wqb, wkb, wvb, wob, x, xT, rpe, rpetab);
    gemm_q<<<dim3(32, 4, 4), 256, 0, stream>>>(xT, wqb, bq, q_b);
    dwln<<<256, 256, 0, stream>>>(q_b, wdw, bdw, lng, lnb, wpj, x,
                                  outp + (1 << 20), outp + (1 << 20) + 32768, pos_sc, xsT);
    gemm_kv<<<dim3(32, 4, 4), 256, 0, stream>>>(xsT, wkb, bk, kbt, wvb, bv, vbs);
    attn_part<<<dim3(16, 32, 4), 256, 0, stream>>>(q_b, kbt, vbs, pos_sc, rpetab, partO, lbuf);
    gemm_oc<<<dim3(32, 4, 4), 256, 0, stream>>>(partO, lbuf, wob, bo, outp);
}

// Round 14
// 163.790 us; speedup vs baseline: 1.0908x; 1.0908x over previous
//
#include <hip/hip_runtime.h>
#include <math.h>

#define CK __restrict__

constexpr int CH = 256;
constexpr int HW = 1024;   // 32*32

typedef __attribute__((ext_vector_type(8))) short short8;
typedef __attribute__((ext_vector_type(4))) float f32x4;
typedef __attribute__((ext_vector_type(2))) float v2f;

__device__ __forceinline__ ushort f2b(float x) {   // fp32 -> bf16 RNE
    union { float f; unsigned int u; } a; a.f = x;
    unsigned int r = (a.u + 0x7FFFu + ((a.u >> 16) & 1u)) >> 16;
    return (ushort)r;
}
__device__ __forceinline__ short8 ld8(const ushort* p) { return *(const short8*)p; }
__device__ __forceinline__ float u2f(unsigned int u) {
    union { unsigned int u; float f; } a; a.u = u; return a.f;
}
__device__ __forceinline__ float b2f(ushort us) { return u2f((unsigned int)us << 16); }

// ---------------------------------------------------------------------------
// prep: blocks 0..255  : four 256x256 weights -> bf16
//       blocks 256..383: x fp32 [b][c][n] -> xT bf16 [b][n][c]
//       blocks 384..391: rpe head -> padded bf16 x-pair table, pitch 67
// ---------------------------------------------------------------------------
__global__ __launch_bounds__(256) void prep(const float* CK w0, const float* CK w1,
                                            const float* CK w2, const float* CK w3,
                                            ushort* CK o0, ushort* CK o1,
                                            ushort* CK o2, ushort* CK o3,
                                            const float* CK x, ushort* CK xT,
                                            const float* CK rpe, unsigned int* CK rpetab) {
    const int bid = blockIdx.x, t = threadIdx.x;
    if (bid < 256) {
        const float* src; ushort* dst;
        switch (bid >> 6) {
            case 0: src = w0; dst = o0; break;
            case 1: src = w1; dst = o1; break;
            case 2: src = w2; dst = o2; break;
            default: src = w3; dst = o3; break;
        }
        const int i = (bid & 63) * 256 + t;
        float4 v = ((const float4*)src)[i];
        ushort4 r; r.x = f2b(v.x); r.y = f2b(v.y); r.z = f2b(v.z); r.w = f2b(v.w);
        ((ushort4*)dst)[i] = r;
    } else if (bid < 384) {
        const int b2 = bid - 256;          // 0..127
        const int c8 = b2 & 31, b = b2 >> 5;
        for (int nn = 0; nn < 4; nn++) {
            const int n = nn * 256 + t;
            union { ushort u[8]; short8 s; } pk;
#pragma unroll
            for (int j = 0; j < 8; j++) pk.u[j] = f2b(x[(b * 256 + c8 * 8 + j) * HW + n]);
            *(short8*)(xT + b * 262144 + n * 256 + c8 * 8) = pk.s;
        }
    } else {
        const int h = bid - 384;           // head 0..7
        const float* rp = rpe + h * 3969;
        unsigned int* dst = rpetab + h * 4356;
        for (int i = t; i < 4356; i += 256) {
            int y = i / 67, x2 = i - y * 67;
            int yy = y - 1, xx = x2 - 1;
            bool vy = (yy >= 0) && (yy < 63) && (y < 65);
            float a  = (vy && xx >= 0 && xx < 63) ? rp[yy * 63 + xx] : 0.f;
            float bb = (vy && xx >= -1 && xx < 62) ? rp[yy * 63 + xx + 1] : 0.f;
            dst[i] = (unsigned int)f2b(a) | ((unsigned int)f2b(bb) << 16);
        }
    }
}

// ---------------------------------------------------------------------------
// MFMA GEMM (64x64 block, 4 waves of 32x32, 2x2 indep acc chains — the
// proven r12 shape; n-split regressed twice, do not revisit).
// bf16 out: Q = W*xT + bias.  grid (16 nt, 4 mt, 4 b).
// ---------------------------------------------------------------------------
__global__ __launch_bounds__(256) void gemm_q(const ushort* CK AT, const ushort* CK W,
                                              const float* CK bias, ushort* CK Y) {
    const int b = blockIdx.z;
    const int t = threadIdx.x, w = t >> 6, l = t & 63;
    const int lm = l & 15, qd = l >> 4;
    const int m0 = blockIdx.y * 64 + (w & 1) * 32;
    const int n0 = blockIdx.x * 64 + (w >> 1) * 32;
    const ushort* A = AT + b * 262144 + n0 * 256;
    const ushort* Bm = W + m0 * 256;
    f32x4 acc[2][2] = {};
#pragma unroll
    for (int k0 = 0; k0 < 8; k0++) {
        const int ko = k0 * 32 + qd * 8;
        short8 a0 = ld8(A + lm * 256 + ko);
        short8 a1 = ld8(A + (16 + lm) * 256 + ko);
        short8 b0 = ld8(Bm + lm * 256 + ko);
        short8 b1 = ld8(Bm + (16 + lm) * 256 + ko);
        acc[0][0] = __builtin_amdgcn_mfma_f32_16x16x32_bf16(a0, b0, acc[0][0], 0, 0, 0);
        acc[0][1] = __builtin_amdgcn_mfma_f32_16x16x32_bf16(a0, b1, acc[0][1], 0, 0, 0);
        acc[1][0] = __builtin_amdgcn_mfma_f32_16x16x32_bf16(a1, b0, acc[1][0], 0, 0, 0);
        acc[1][1] = __builtin_amdgcn_mfma_f32_16x16x32_bf16(a1, b1, acc[1][1], 0, 0, 0);
    }
#pragma unroll
    for (int in = 0; in < 2; in++)
#pragma unroll
        for (int im = 0; im < 2; im++) {
            const int m = m0 + im * 16 + lm;
            const float bs = bias[m];
            ushort4 r;
            r.x = f2b(acc[in][im][0] + bs); r.y = f2b(acc[in][im][1] + bs);
            r.z = f2b(acc[in][im][2] + bs); r.w = f2b(acc[in][im][3] + bs);
            *(ushort4*)(Y + b * 262144 + m * HW + n0 + in * 16 + qd * 4) = r;
        }
}

// ---------------------------------------------------------------------------
// Fused K+V MFMA GEMM (r12 shape), bf16 fragment-linear outputs.
// ---------------------------------------------------------------------------
__global__ __launch_bounds__(256) void gemm_kv(const ushort* CK AT,
                                               const ushort* CK Wk, const float* CK bk, ushort* CK kbt,
                                               const ushort* CK Wv, const float* CK bv, ushort* CK vbs) {
    const int b = blockIdx.z;
    const int t = threadIdx.x, w = t >> 6, l = t & 63;
    const int lm = l & 15, qd = l >> 4;
    const int m0 = blockIdx.y * 64 + (w & 1) * 32;
    const int n0 = blockIdx.x * 64 + (w >> 1) * 32;
    const ushort* A = AT + b * 262144 + n0 * 256;
    const ushort* Bk = Wk + m0 * 256;
    const ushort* Bv = Wv + m0 * 256;
    f32x4 akT[2][2] = {}, av[2][2] = {};
#pragma unroll
    for (int k0 = 0; k0 < 8; k0++) {
        const int ko = k0 * 32 + qd * 8;
        short8 a0 = ld8(A + lm * 256 + ko);
        short8 a1 = ld8(A + (16 + lm) * 256 + ko);
        short8 k0f = ld8(Bk + lm * 256 + ko);
        short8 k1f = ld8(Bk + (16 + lm) * 256 + ko);
        short8 v0f = ld8(Bv + lm * 256 + ko);
        short8 v1f = ld8(Bv + (16 + lm) * 256 + ko);
        akT[0][0] = __builtin_amdgcn_mfma_f32_16x16x32_bf16(k0f, a0, akT[0][0], 0, 0, 0);
        akT[0][1] = __builtin_amdgcn_mfma_f32_16x16x32_bf16(k0f, a1, akT[0][1], 0, 0, 0);
        akT[1][0] = __builtin_amdgcn_mfma_f32_16x16x32_bf16(k1f, a0, akT[1][0], 0, 0, 0);
        akT[1][1] = __builtin_amdgcn_mfma_f32_16x16x32_bf16(k1f, a1, akT[1][1], 0, 0, 0);
        av[0][0] = __builtin_amdgcn_mfma_f32_16x16x32_bf16(a0, v0f, av[0][0], 0, 0, 0);
        av[0][1] = __builtin_amdgcn_mfma_f32_16x16x32_bf16(a0, v1f, av[0][1], 0, 0, 0);
        av[1][0] = __builtin_amdgcn_mfma_f32_16x16x32_bf16(a1, v0f, av[1][0], 0, 0, 0);
        av[1][1] = __builtin_amdgcn_mfma_f32_16x16x32_bf16(a1, v1f, av[1][1], 0, 0, 0);
    }
#pragma unroll
    for (int im = 0; im < 2; im++)
#pragma unroll
        for (int in = 0; in < 2; in++) {
            {   // K: lane holds K[c0+r][n]
                const int c0 = m0 + im * 16 + qd * 4;
                const int n  = n0 + in * 16 + lm;
                const int bh = b * 8 + (c0 >> 5);
                const int qdk = (c0 & 31) >> 3, co4 = c0 & 7;
                const int nc = n >> 7, nbk = (n >> 4) & 7, lmk = n & 15;
                const float4 bks = *(const float4*)(bk + c0);
                ushort4 r4;
                r4.x = f2b(akT[im][in][0] + bks.x);
                r4.y = f2b(akT[im][in][1] + bks.y);
                r4.z = f2b(akT[im][in][2] + bks.z);
                r4.w = f2b(akT[im][in][3] + bks.w);
                *(ushort4*)(kbt + ((bh * 8 + nc) * 512 + nbk * 64 + qdk * 16 + lmk) * 8 + co4) = r4;
            }
            {   // V: lane holds V[c][nbase+r]
                const int c = m0 + im * 16 + lm;
                const int bh = b * 8 + (c >> 5);
                const float bs = bv[c];
                const int cb = (c & 31) >> 4, lmv = c & 15;
                const int nbase = n0 + in * 16 + qd * 4;
                const int nc = nbase >> 7, kc = (nbase >> 5) & 3;
                const int qdv = (nbase >> 3) & 3, co0 = nbase & 7;
                ushort4 r4;
                r4.x = f2b(av[in][im][0] + bs); r4.y = f2b(av[in][im][1] + bs);
                r4.z = f2b(av[in][im][2] + bs); r4.w = f2b(av[in][im][3] + bs);
                *(ushort4*)(vbs + ((bh * 8 + nc) * 512 + (cb * 4 + kc) * 64 + qdv * 16 + lmv) * 8 + co0) = r4;
            }
        }
}

// ---------------------------------------------------------------------------
// FUSED depthwise-5x5 + LayerNorm + GELU + proj + tanh -> pos + bilinear
// sample (r12, unchanged).
// ---------------------------------------------------------------------------
__global__ __launch_bounds__(256) void dwln(const ushort* CK q, const float* CK wdw,
                                            const float* CK bdw, const float* CK ln_g,
                                            const float* CK ln_b, const float* CK wpj,
                                            const float* CK x,
                                            float* CK out_pos, float* CK out_ref,
                                            float2* CK pos_sc, ushort* CK xsT) {
    __shared__ __align__(16) ushort qs[64 * 218];   // [ch][6 rows x 36 cols], pitch 218
    __shared__ __align__(16) float offs[64][68];    // [pix][ch], pitch 68
    const int bid = blockIdx.x, t = threadIdx.x;
    const int bg = bid >> 4, rp = bid & 15;         // rp = 2-row strip

    {
        const int ch = t & 63;
        const int r6a = t >> 6;                     // 0..3
#pragma unroll
        for (int pass = 0; pass < 2; pass++) {
            const int r6 = (pass == 0) ? r6a : (4 + r6a);
            if (pass == 1 && r6a >= 2) break;
            const int grow = rp * 2 - 2 + r6;
            unsigned int* dst = (unsigned int*)(qs + ch * 218 + r6 * 36);
            if (grow >= 0 && grow <= 31) {
                const unsigned int* src = (const unsigned int*)(q + (bg * 64 + ch) * 1024 + grow * 32);
                dst[0] = 0;
#pragma unroll
                for (int k2 = 0; k2 < 16; k2++) dst[1 + k2] = src[k2];   // cols 0..31
                dst[17] = 0;
            } else {
#pragma unroll
                for (int k2 = 0; k2 < 18; k2++) dst[k2] = 0;
            }
        }
    }
    __syncthreads();

    {
        const int ch = t >> 2, pg = t & 3;
        const int pr = pg >> 1, c0 = (pg & 1) * 16;
        float w[25];
#pragma unroll
        for (int i = 0; i < 25; i++) w[i] = wdw[ch * 25 + i];
        const float bb = bdw[ch];
        float nb[5][20];
#pragma unroll
        for (int r = 0; r < 5; r++) {
            const unsigned int* row = (const unsigned int*)(qs + ch * 218 + (pr + r) * 36 + c0);
#pragma unroll
            for (int u = 0; u < 10; u++) {
                const unsigned int v = row[u];
                nb[r][u * 2]     = u2f(v << 16);
                nb[r][u * 2 + 1] = u2f(v & 0xFFFF0000u);
            }
        }
#pragma unroll
        for (int j = 0; j < 16; j++) {
            float s = bb;
#pragma unroll
            for (int ky = 0; ky < 5; ky++)
#pragma unroll
                for (int kx = 0; kx < 5; kx++) s += nb[ky][j + kx] * w[ky * 5 + kx];
            offs[pr * 32 + c0 + j][ch] = s;
        }
    }
    __syncthreads();

    const int pix_l = t >> 2, qtr = t & 3;
    const int n = rp * 64 + pix_l;
    const int gid = bg * 1024 + n;
    const int c0 = qtr * 16;
    float v[16];
    {
        const float4* ov = (const float4*)&offs[pix_l][c0];
        const float4 V0 = ov[0], V1 = ov[1], V2 = ov[2], V3 = ov[3];
        v[0] = V0.x;  v[1] = V0.y;  v[2] = V0.z;  v[3] = V0.w;
        v[4] = V1.x;  v[5] = V1.y;  v[6] = V1.z;  v[7] = V1.w;
        v[8] = V2.x;  v[9] = V2.y;  v[10] = V2.z; v[11] = V2.w;
        v[12] = V3.x; v[13] = V3.y; v[14] = V3.z; v[15] = V3.w;
    }
    float s1 = 0.f;
#pragma unroll
    for (int j = 0; j < 16; j++) s1 += v[j];
    s1 += __shfl_xor(s1, 1); s1 += __shfl_xor(s1, 2);
    const float mean = s1 * 0.015625f;
    float s2 = 0.f;
#pragma unroll
    for (int j = 0; j < 16; j++) { float d = v[j] - mean; s2 += d * d; }
    s2 += __shfl_xor(s2, 1); s2 += __shfl_xor(s2, 2);
    const float rs = rsqrtf(s2 * 0.015625f + 1e-5f);
    float p0 = 0.f, p1 = 0.f;
#pragma unroll
    for (int j = 0; j < 16; j++) {
        float vv = (v[j] - mean) * rs * ln_g[c0 + j] + ln_b[c0 + j];
        float gl = 0.5f * vv * (1.f + erff(vv * 0.70710678118654752f));
        p0 += gl * wpj[c0 + j];
        p1 += gl * wpj[64 + c0 + j];
    }
    p0 += __shfl_xor(p0, 1); p0 += __shfl_xor(p0, 2);
    p1 += __shfl_xor(p1, 1); p1 += __shfl_xor(p1, 2);
    const int ii = n >> 5, jj = n & 31;
    const float r0 = (jj + 0.5f) * 0.0625f - 1.f;   // ref ch0 <- column (meshgrid-xy)
    const float r1 = (ii + 0.5f) * 0.0625f - 1.f;   // ref ch1 <- row
    const float pos0 = tanhf(p0) * 0.0625f + r0;
    const float pos1 = tanhf(p1) * 0.0625f + r1;
    if (qtr == 0) {
        out_pos[gid * 2] = pos0; out_pos[gid * 2 + 1] = pos1;
        out_ref[gid * 2] = r0;   out_ref[gid * 2 + 1] = r1;
        pos_sc[gid].x = pos0 * 15.5f; pos_sc[gid].y = pos1 * 15.5f;
    }
    const float gx = (pos1 + 1.f) * 15.5f, gy = (pos0 + 1.f) * 15.5f;
    const float x0f = floorf(gx), y0f = floorf(gy);
    const float wx1 = gx - x0f, wx0 = 1.f - wx1, wy1 = gy - y0f, wy0 = 1.f - wy1;
    const bool vx0 = (x0f >= 0.f) && (x0f <= 31.f);
    const bool vx1 = (x0f >= -1.f) && (x0f <= 30.f);
    const bool vy0 = (y0f >= 0.f) && (y0f <= 31.f);
    const bool vy1 = (y0f >= -1.f) && (y0f <= 30.f);
    const int xi0 = (int)fminf(fmaxf(x0f, 0.f), 31.f);
    const int xi1 = (int)fminf(fmaxf(x0f + 1.f, 0.f), 31.f);
    const int yi0 = (int)fminf(fmaxf(y0f, 0.f), 31.f);
    const int yi1 = (int)fminf(fmaxf(y0f + 1.f, 0.f), 31.f);
    const float w00 = (vy0 && vx0) ? wy0 * wx0 : 0.f;
    const float w01 = (vy0 && vx1) ? wy0 * wx1 : 0.f;
    const float w10 = (vy1 && vx0) ? wy1 * wx0 : 0.f;
    const float w11 = (vy1 && vx1) ? wy1 * wx1 : 0.f;
    const int o00 = yi0 * 32 + xi0, o01 = yi0 * 32 + xi1;
    const int o10 = yi1 * 32 + xi0, o11 = yi1 * 32 + xi1;
    const int b = bg >> 2, g = bg & 3;
    const float* xb = x + bg * 64 * HW;
    ushort* xo = xsT + b * 262144 + n * 256 + g * 64 + c0;
#pragma unroll
    for (int j4 = 0; j4 < 4; j4++) {
        ushort4 r4;
        float vals[4];
#pragma unroll
        for (int j = 0; j < 4; j++) {
            const float* p = xb + (c0 + j4 * 4 + j) * HW;
            vals[j] = w00 * p[o00] + w01 * p[o01] + w10 * p[o10] + w11 * p[o11];
        }
        r4.x = f2b(vals[0]); r4.y = f2b(vals[1]); r4.z = f2b(vals[2]); r4.w = f2b(vals[3]);
        *(ushort4*)(xo + j4 * 4) = r4;
    }
}

// ---------------------------------------------------------------------------
// MFMA flash attention, n-split x4, fixed-reference softmax.
// 1-D grid 2048, XCD-swizzled decode: bid = mt*128 + (bh*4 + quarter) so the
// 16 m-tile blocks sharing one (bh,quarter) K/V chunk are all == r (mod 8)
// -> same XCD under round-robin dispatch -> chunk lives in ONE L2.
// ---------------------------------------------------------------------------
__global__ __launch_bounds__(256, 4) void attn_part(const ushort* CK q, const ushort* CK kbt,
                                                    const ushort* CK vbs, const float2* CK pos_sc,
                                                    const unsigned int* CK rpetab,
                                                    ushort* CK partO, float* CK lbuf) {
    __shared__ __align__(16) unsigned int rpe_pr[4356];      // 65 x pitch-67 bf16-pairs
    __shared__ __align__(16) ushort Pl[4][1088];             // per-wave 4 blk x 272
    const int bid = blockIdx.x;
    const int mt = bid >> 7;                 // m-tile 0..15
    const int r_ = bid & 127;                // (bh, quarter) id
    const int bh = r_ >> 2, quarter = r_ & 3;
    const int b = bh >> 3, nh = bh & 7, bg = bh >> 1;
    const int t = threadIdx.x;
    const int w = t >> 6, l = t & 63;
    const int lm = l & 15, qd = l >> 4;

    {
        const uint4* src4 = (const uint4*)(rpetab + nh * 4356);
        uint4* dst4 = (uint4*)rpe_pr;
        for (int i = t; i < 1089; i += 256) dst4[i] = src4[i];
    }
    __syncthreads();

    const int m = mt * 64 + w * 16 + lm;
    short8 qf;
    {
        union { ushort u[8]; short8 s; } pk;
        const ushort* qb = q + (b * 256 + nh * 32) * HW + m;
#pragma unroll
        for (int j = 0; j < 8; j++) pk.u[j] = qb[(qd * 8 + j) * HW];
        qf = pk.s;
    }
    const float qg0 = ((m & 31) + 0.5f) * 0.0625f - 1.f;
    const float qg1 = ((m >> 5) + 0.5f) * 0.0625f - 1.f;
    const float ax = 31.f + 15.5f * qg1;   // gx = ax - sc_pos1  (>= 0 always)
    const float ay = 31.f + 15.5f * qg0;   // gy = ay - sc_pos0  (>= 0 always)

    f32x4 oacc0 = {0.f, 0.f, 0.f, 0.f}, oacc1 = {0.f, 0.f, 0.f, 0.f};
    float rsum = 0.f;
    ushort* PlW = Pl[w];
    const float2* pbase = pos_sc + bg * 1024;

    for (int nc = quarter * 2; nc < quarter * 2 + 2; nc++) {
        const ushort* kg = kbt + (bh * 8 + nc) * 4096;
        const ushort* vg = vbs + (bh * 8 + nc) * 4096;

#pragma unroll
        for (int g = 0; g < 2; g++) {                 // 64-n groups
            f32x4 sT[4];
#pragma unroll
            for (int s = 0; s < 4; s++) {
                const int nb = g * 4 + s;
                sT[s] = __builtin_amdgcn_mfma_f32_16x16x32_bf16(
                            ld8(kg + (nb * 64 + l) * 8), qf,
                            (f32x4){0.f, 0.f, 0.f, 0.f}, 0, 0, 0);
            }
#pragma unroll
            for (int s = 0; s < 4; s++) {
                const float4* pp = (const float4*)(pbase + nc * 128 + (g * 4 + s) * 16 + qd * 4);
                const float4 pa = pp[0], pb_ = pp[1];
                const float psx[4] = {pa.x, pa.z, pb_.x, pb_.z};
                const float psy[4] = {pa.y, pa.w, pb_.y, pb_.w};
#pragma unroll
                for (int rp = 0; rp < 2; rp++) {
                    v2f gx = {ax - psy[rp * 2], ax - psy[rp * 2 + 1]};
                    v2f gy = {ay - psx[rp * 2], ay - psx[rp * 2 + 1]};
                    const int xi0 = (int)gx.x, xi1 = (int)gx.y;   // trunc == floor (>=0)
                    const int yi0 = (int)gy.x, yi1 = (int)gy.y;
                    v2f wx = gx - (v2f){(float)xi0, (float)xi1};
                    v2f wy = gy - (v2f){(float)yi0, (float)yi1};
                    const int idxA = yi0 * 67 + xi0 + 68;
                    const int idxB = yi1 * 67 + xi1 + 68;
                    const unsigned int a0 = rpe_pr[idxA], a1 = rpe_pr[idxA + 67];
                    const unsigned int b0 = rpe_pr[idxB], b1 = rpe_pr[idxB + 67];
                    v2f tA = {u2f(a0 << 16), u2f(a0 & 0xFFFF0000u)};
                    v2f bA = {u2f(a1 << 16), u2f(a1 & 0xFFFF0000u)};
                    v2f tB = {u2f(b0 << 16), u2f(b0 & 0xFFFF0000u)};
                    v2f bB = {u2f(b1 << 16), u2f(b1 & 0xFFFF0000u)};
                    v2f vA = tA + wy.x * (bA - tA);
                    v2f vB = tB + wy.y * (bB - tB);
                    const float biasA = vA.x + wx.x * (vA.y - vA.x);
                    const float biasB = vB.x + wx.y * (vB.y - vB.x);
                    sT[s][rp * 2]     = sT[s][rp * 2]     * 0.17677669529663687f + biasA;
                    sT[s][rp * 2 + 1] = sT[s][rp * 2 + 1] * 0.17677669529663687f + biasB;
                }
            }
            // P = exp(s) -> wave-private LDS; per-lane denominator accumulate
#pragma unroll
            for (int s = 0; s < 4; s++) {
                float e0 = __expf(sT[s][0]);
                float e1 = __expf(sT[s][1]);
                float e2 = __expf(sT[s][2]);
                float e3 = __expf(sT[s][3]);
                rsum += (e0 + e1) + (e2 + e3);
                uint2 pk;
                pk.x = (unsigned int)f2b(e0) | ((unsigned int)f2b(e1) << 16);
                pk.y = (unsigned int)f2b(e2) | ((unsigned int)f2b(e3) << 16);
                *(uint2*)(PlW + s * 272 + l * 4) = pk;
            }
#pragma unroll
            for (int kc = 0; kc < 2; kc++) {
                const ushort* pb2 = PlW + (kc * 2 + (qd >> 1)) * 272 + (qd & 1) * 128 + lm * 4;
                union { uint2 u[2]; short8 s; } pfu;
                pfu.u[0] = *(const uint2*)pb2;
                pfu.u[1] = *(const uint2*)(pb2 + 64);
                const int kv = g * 2 + kc;
                oacc0 = __builtin_amdgcn_mfma_f32_16x16x32_bf16(ld8(vg + (kv * 64 + l) * 8), pfu.s, oacc0, 0, 0, 0);
                oacc1 = __builtin_amdgcn_mfma_f32_16x16x32_bf16(ld8(vg + ((4 + kv) * 64 + l) * 8), pfu.s, oacc1, 0, 0, 0);
            }
        }
    }

    // single cross-lane denominator reduction at the end
    rsum += __shfl_xor(rsum, 16);
    rsum += __shfl_xor(rsum, 32);

    ushort* po = partO + (((quarter * 32 + bh) * 1024 + m) * 32) + qd * 4;
    ushort4 r04, r14;
    r04.x = f2b(oacc0[0]); r04.y = f2b(oacc0[1]); r04.z = f2b(oacc0[2]); r04.w = f2b(oacc0[3]);
    r14.x = f2b(oacc1[0]); r14.y = f2b(oacc1[1]); r14.z = f2b(oacc1[2]); r14.w = f2b(oacc1[3]);
    *(ushort4*)po = r04;
    *(ushort4*)(po + 16) = r14;
    if (qd == 0) lbuf[(quarter * 32 + bh) * 1024 + m] = rsum;
}

// ---------------------------------------------------------------------------
// Output GEMM with fused 4-way combine (r12 shape: 64x64, grid (16,4,4)).
// ---------------------------------------------------------------------------
__global__ __launch_bounds__(256) void gemm_oc(const ushort* CK partO, const float* CK lbuf,
                                               const ushort* CK W, const float* CK bias,
                                               float* CK Y) {
    __shared__ __align__(16) float ew[64][8];      // 2 KB: 1/sum_l per (pix, head)
    const int b = blockIdx.z;
    const int t = threadIdx.x, w = t >> 6, l = t & 63;
    const int lm = l & 15, qd = l >> 4;
    const int m0 = blockIdx.y * 64 + (w & 1) * 32;
    const int n0 = blockIdx.x * 64 + (w >> 1) * 32;
    const int nblk = blockIdx.x * 64;

    for (int p = t; p < 512; p += 256) {
        const int pix = p >> 3, head = p & 7;
        const int mg = nblk + pix;
        const int bh = b * 8 + head;
        float den = 0.f;
#pragma unroll
        for (int q2 = 0; q2 < 4; q2++) den += lbuf[(q2 * 32 + bh) * 1024 + mg];
        ew[pix][head] = 1.f / den;
    }
    __syncthreads();

    const ushort* Bm = W + m0 * 256;
    f32x4 acc[2][2] = {};
#pragma unroll
    for (int k0 = 0; k0 < 8; k0++) {
        const int ko = k0 * 32 + qd * 8;
        short8 af[2];
#pragma unroll
        for (int half = 0; half < 2; half++) {
            const int pix_l = (w >> 1) * 32 + half * 16 + lm;
            const int mg = nblk + pix_l;
            const ushort* pbq = partO + ((b * 8 + k0) * 1024 + mg) * 32 + qd * 8;
            const float inv = ew[pix_l][k0];
            float a8[8] = {};
#pragma unroll
            for (int q2 = 0; q2 < 4; q2++) {
                union { ushort u[8]; short8 s; } pv;
                pv.s = ld8(pbq + q2 * 1048576);
#pragma unroll
                for (int j = 0; j < 8; j++) a8[j] += b2f(pv.u[j]);
            }
            union { ushort u[8]; short8 s; } out;
#pragma unroll
            for (int j = 0; j < 8; j++) out.u[j] = f2b(a8[j] * inv);
            af[half] = out.s;
        }
        short8 b0 = ld8(Bm + lm * 256 + ko);
        short8 b1 = ld8(Bm + (16 + lm) * 256 + ko);
        acc[0][0] = __builtin_amdgcn_mfma_f32_16x16x32_bf16(af[0], b0, acc[0][0], 0, 0, 0);
        acc[0][1] = __builtin_amdgcn_mfma_f32_16x16x32_bf16(af[0], b1, acc[0][1], 0, 0, 0);
        acc[1][0] = __builtin_amdgcn_mfma_f32_16x16x32_bf16(af[1], b0, acc[1][0], 0, 0, 0);
        acc[1][1] = __builtin_amdgcn_mfma_f32_16x16x32_bf16(af[1], b1, acc[1][1], 0, 0, 0);
    }
#pragma unroll
    for (int in = 0; in < 2; in++)
#pragma unroll
        for (int im = 0; im < 2; im++) {
            const int mo = m0 + im * 16 + lm;
            const float bs = bias[mo];
            float4 r;
            r.x = acc[in][im][0] + bs; r.y = acc[in][im][1] + bs;
            r.z = acc[in][im][2] + bs; r.w = acc[in][im][3] + bs;
            *(float4*)(Y + b * 262144 + mo * HW + n0 + in * 16 + qd * 4) = r;
        }
}

// ---------------------------------------------------------------------------
extern "C" void kernel_launch(void* const* d_in, const int* in_sizes, int n_in,
                              void* d_out, int out_size, void* d_ws, size_t ws_size,
                              hipStream_t stream) {
    (void)in_sizes; (void)n_in; (void)out_size; (void)ws_size;
    const float* x   = (const float*)d_in[0];
    const float* wq  = (const float*)d_in[1];
    const float* bq  = (const float*)d_in[2];
    const float* wdw = (const float*)d_in[3];
    const float* bdw = (const float*)d_in[4];
    const float* lng = (const float*)d_in[5];
    const float* lnb = (const float*)d_in[6];
    const float* wpj = (const float*)d_in[7];
    const float* wk  = (const float*)d_in[8];
    const float* bk  = (const float*)d_in[9];
    const float* wv  = (const float*)d_in[10];
    const float* bv  = (const float*)d_in[11];
    const float* wo  = (const float*)d_in[12];
    const float* bo  = (const float*)d_in[13];
    const float* rpe = (const float*)d_in[14];
    float* outp = (float*)d_out;
    char* base = (char*)d_ws;
    const size_t MB = 1 << 20;

    ushort* q_b    = (ushort*)(base);                       // 2 MB  bf16 q
    ushort* kbt    = (ushort*)(base + 2 * MB);              // 2 MB
    ushort* vbs    = (ushort*)(base + 4 * MB);              // 2 MB
    // overlay @6MB..14MB: {xT 2MB @10, xsT 2MB @12} then partO 8MB @6
    ushort* xT     = (ushort*)(base + 10 * MB);
    ushort* xsT    = (ushort*)(base + 12 * MB);
    ushort* partO  = (ushort*)(base + 6 * MB);
    float*  lbuf   = (float*)(base + 14 * MB);              // 512 KB
    ushort* wqb    = (ushort*)(base + 15 * MB);
    ushort* wkb    = (ushort*)(base + 15 * MB + 131072);
    ushort* wvb    = (ushort*)(base + 15 * MB + 262144);
    ushort* wob    = (ushort*)(base + 15 * MB + 393216);
    float2* pos_sc = (float2*)(base + 15 * MB + 524288);    // 128 KB
    unsigned int* rpetab = (unsigned int*)(base + 15 * MB + 655360);  // 139 KB

    prep<<<392, 256, 0, stream>>>(wq, wk, wv, wo, wqb, wkb, wvb, wob, x, xT, rpe, rpetab);
    gemm_q<<<dim3(16, 4, 4), 256, 0, stream>>>(xT, wqb, bq, q_b);
    dwln<<<256, 256, 0, stream>>>(q_b, wdw, bdw, lng, lnb, wpj, x,
                                  outp + (1 << 20), outp + (1 << 20) + 32768, pos_sc, xsT);
    gemm_kv<<<dim3(16, 4, 4), 256, 0, stream>>>(xsT, wkb, bk, kbt, wvb, bv, vbs);
    attn_part<<<2048, 256, 0, stream>>>(q_b, kbt, vbs, pos_sc, rpetab, partO, lbuf);
    gemm_oc<<<dim3(16, 4, 4), 256, 0, stream>>>(partO, lbuf, wob, bo, outp);
}